// Round 10
// baseline (300.623 us; speedup 1.0000x reference)
//
#include <hip/hip_runtime.h>
#include <hip/hip_bf16.h>
#include <math.h>

#define BB 8
#define CCH 36
#define HH 256
#define WW 256
#define EE 6
#define TDIM 32
#define HID 72
// ws layout: floats [0,288) avg; [288,576) max; [576,624) gates.
// bytes: wt1 frags at 4096 (360 x 1024B); wt2 frags at 372736 (378 x 1024B).
#define WS_GATES (BB*CCH*2)
#define WT1_OFF 4096
#define WT2_OFF (4096 + 368640)

// conv geometry: 16w x 8t output tile, 4 waves
#define TW 16
#define TH 8
#define XR 12
#define XC 20
#define TR 10
#define TC 18

typedef __attribute__((ext_vector_type(8))) short bf16x8;
typedef __attribute__((ext_vector_type(4))) float f32x4;

static __device__ __forceinline__ unsigned short f2bf(float f) {
  __hip_bfloat16 h = __float2bfloat16(f);   // RNE; compiler emits HW cvt
  return *(unsigned short*)&h;
}
// sigmoid-form GELU: x * rcp(1 + exp(-2u)), 2u = x*(1.5958 + 0.07135 x^2).
// No clamp needed: exp->inf => rcp->0 => result 0; exp->0 => result x. |err|~3e-4.
static __device__ __forceinline__ float gelu_fast(float x) {
  float n2u = x * (-1.5957691216f - 0.0713548162f * x * x);
  float r = __builtin_amdgcn_rcpf(1.f + __expf(n2u));
  return x * r;
}

// ---------------- Kernel 1: pool (blocks 0..287) + weight transform (288..1043) ----
// wt1 frag f = ((e*3+dx)*4+kc)*5+mt; elem = f*512 + lane*8 + j.
//   co = mt*16 + (lane&15); k = kc*32 + (lane>>4)*8 + j; k = dy*40+ci, K=120 (pads ZERO).
// wt2 frag f = ((e*3+dx)*7+kc)*3+mt; k = dy*72+ci, K=216 (pads ZERO).
__global__ __launch_bounds__(256) void poolwx_kernel(const float* __restrict__ x,
                                                     const float* __restrict__ w1,
                                                     const float* __restrict__ w2,
                                                     float* __restrict__ ws,
                                                     unsigned short* __restrict__ wt1,
                                                     unsigned short* __restrict__ wt2) {
  if (blockIdx.x < 288) {
    const int bc = blockIdx.x;
    const float* p = x + (size_t)bc * (HH * WW);
    float s = 0.f, m = -INFINITY;
    for (int i = threadIdx.x; i < (HH * WW) / 4; i += 256) {
      float4 v = ((const float4*)p)[i];
      s += v.x + v.y + v.z + v.w;
      m = fmaxf(m, fmaxf(fmaxf(v.x, v.y), fmaxf(v.z, v.w)));
    }
    for (int off = 32; off; off >>= 1) {
      s += __shfl_down(s, off);
      m = fmaxf(m, __shfl_down(m, off));
    }
    __shared__ float ss[4], sm[4];
    int wid = threadIdx.x >> 6, lane = threadIdx.x & 63;
    if (lane == 0) { ss[wid] = s; sm[wid] = m; }
    __syncthreads();
    if (threadIdx.x == 0) {
      float S = ss[0] + ss[1] + ss[2] + ss[3];
      float M = fmaxf(fmaxf(sm[0], sm[1]), fmaxf(sm[2], sm[3]));
      ws[bc] = S * (1.f / (HH * WW));
      ws[BB * CCH + bc] = M;
    }
    return;
  }
  int i = (blockIdx.x - 288) * 256 + threadIdx.x;
  const int n1 = 360 * 512;
  if (i < n1) {
    int j = i & 7;
    int lane = (i >> 3) & 63;
    int f = i >> 9;
    int mt = f % 5;  f /= 5;
    int kc = f % 4;  f /= 4;
    int dx = f % 3;  int e = f / 3;
    int co = mt * 16 + (lane & 15);
    int k = kc * 32 + (lane >> 4) * 8 + j;
    int dy = k / 40, ci = k % 40;
    float v = 0.f;
    if (co < HID && k < 120 && ci < CCH)
      v = w1[(((size_t)(e * HID + co) * CCH + ci) * 3 + dy) * 3 + dx];
    wt1[i] = f2bf(v);
  }
  const int n2 = 378 * 512;
  if (i < n2) {
    int j = i & 7;
    int lane = (i >> 3) & 63;
    int f = i >> 9;
    int mt = f % 3;  f /= 3;
    int kc = f % 7;  f /= 7;
    int dx = f % 3;  int e = f / 3;
    int co = mt * 16 + (lane & 15);
    int k = kc * 32 + (lane >> 4) * 8 + j;
    int dy = k / 72, ci = k % 72;
    float v = 0.f;
    if (co < CCH && k < 216)
      v = w2[(((size_t)(e * CCH + co) * HID + ci) * 3 + dy) * 3 + dx];
    wt2[i] = f2bf(v);
  }
}

// ---------------- Kernel 2: gating MLP + top-2 + loss ----------------
__global__ void gate_kernel(const float* __restrict__ time,
                            const float* __restrict__ time_w,
                            const float* __restrict__ time_b,
                            const float* __restrict__ w1, const float* __restrict__ b1,
                            const float* __restrict__ w2, const float* __restrict__ b2,
                            float* __restrict__ ws, float* __restrict__ loss_out) {
  __shared__ float v[BB * HID];
  __shared__ float h[BB * HID];
  __shared__ float logits[BB * EE];
  const int t = threadIdx.x;
  const float* avg = ws;
  const float* mx = ws + BB * CCH;
  for (int i = t; i < BB * HID; i += blockDim.x) {
    int b = i / HID, c = i % HID;
    float base = (c < CCH) ? avg[b * CCH + c] : mx[b * CCH + (c - CCH)];
    float acc = time_b[c];
    for (int k = 0; k < TDIM; k++) acc += time[b * TDIM + k] * time_w[k * HID + c];
    v[i] = base + acc;
  }
  __syncthreads();
  for (int i = t; i < BB * HID; i += blockDim.x) {
    int b = i / HID, c = i % HID;
    float acc = b1[c];
    for (int k = 0; k < HID; k++) acc += v[b * HID + k] * w1[k * HID + c];
    h[i] = acc > 0.f ? acc : 0.01f * acc;
  }
  __syncthreads();
  for (int i = t; i < BB * EE; i += blockDim.x) {
    int b = i / EE, e = i % EE;
    float acc = b2[e];
    for (int k = 0; k < HID; k++) acc += h[b * HID + k] * w2[k * EE + e];
    logits[i] = acc;
  }
  __syncthreads();
  if (t == 0) {
    float imp[EE], ld[EE];
    for (int e = 0; e < EE; e++) { imp[e] = 0.f; ld[e] = 0.f; }
    for (int b = 0; b < BB; b++) {
      int i1 = -1, i2 = -1;
      float v1 = -1e30f, v2 = -1e30f;
      for (int e = 0; e < EE; e++) {
        float lv = logits[b * EE + e];
        if (lv > v1) { v2 = v1; i2 = i1; v1 = lv; i1 = e; }
        else if (lv > v2) { v2 = lv; i2 = e; }
      }
      float e2 = expf(v2 - v1);
      float g1 = 1.f / (1.f + e2), g2 = e2 / (1.f + e2);
      for (int e = 0; e < EE; e++) ws[WS_GATES + b * EE + e] = 0.f;
      ws[WS_GATES + b * EE + i1] = g1;
      ws[WS_GATES + b * EE + i2] = g2;
      imp[i1] += g1; imp[i2] += g2;
      ld[i1] += 1.f; ld[i2] += 1.f;
    }
    float loss = 0.f;
    {
      float m = 0.f; for (int e = 0; e < EE; e++) m += imp[e]; m /= EE;
      float var = 0.f; for (int e = 0; e < EE; e++) { float d = imp[e] - m; var += d * d; }
      var /= (EE - 1);
      loss += var / (m * m + 1e-10f);
      m = 0.f; for (int e = 0; e < EE; e++) m += ld[e]; m /= EE;
      var = 0.f; for (int e = 0; e < EE; e++) { float d = ld[e] - m; var += d * d; }
      var /= (EE - 1);
      loss += var / (m * m + 1e-10f);
    }
    loss_out[0] = 0.01f * loss;
  }
}

// ---------------- Kernel 3: fused MFMA conv1+GELU+conv2 ----------------
// Tile 16x8, 4 waves. Chunked LDS (16-B lane stride):
//   xs[c8<5][xr][xc][8ci] 19200 B; ts[c9<9][tr][tc][8co] 25920 B + 2880 B junk pad.
// Weight A-fragments stream from L2 via IN-PLACE REGISTER ROTATION:
//   conv1 holds f1[3dx][5mt] (one kc column); each dx's frags are reloaded for
//   kc+1 right after their 15 MFMAs -> reuse distance = 1 kc step (~218 cyc >= L2 lat).
//   conv2 holds f2[7kc][3mt] (one dx batch, issued under GELU); each kc's frags
//   reload for dx+1 after their 6 MFMAs -> reuse distance = 1 dx sweep (~200 cyc).
// Gate folded into T (T = bf16(g*gelu)) so conv2 MFMAs accumulate into yacc directly.
__global__ __launch_bounds__(256, 3) void conv_kernel(
    const float* __restrict__ x,
    const unsigned short* __restrict__ wt1,
    const unsigned short* __restrict__ wt2,
    const float* __restrict__ wsg,
    float* __restrict__ y) {
  __shared__ __align__(16) char lds[48000];   // 19200 xs + 25920 ts + 2880 pad
  char* xsB = lds;
  char* tsB = lds + 19200;

  const int tid = threadIdx.x;
  const int w = tid >> 6;
  const int lane = tid & 63;
  const int l15 = lane & 15;
  const int kl = lane >> 4;
  const int b = blockIdx.y;
  // XCD-chunked swizzle: each XCD gets a contiguous 4-tile-row band.
  const int tileId = (blockIdx.x & 7) * 64 + (blockIdx.x >> 3);
  const int tx0 = (tileId & 15) * TW;
  const int ty0 = (tileId >> 4) * TH;
  const size_t xbase = (size_t)b * (CCH * HH * WW);

  // active experts -> wave-uniform scalars
  int eids[2] = {0, 0};
  float gvals[2] = {0.f, 0.f};
  int ne = 0;
  for (int e = 0; e < EE; e++) {
    float g = wsg[b * EE + e];
    if (g != 0.f && ne < 2) { eids[ne] = e; gvals[ne] = g; ne++; }
  }
  ne = __builtin_amdgcn_readfirstlane(ne);
  const int e0 = __builtin_amdgcn_readfirstlane(eids[0]);
  const int e1 = __builtin_amdgcn_readfirstlane(eids[1]);
  const float g0 = __int_as_float(__builtin_amdgcn_readfirstlane(__float_as_int(gvals[0])));
  const float g1 = __int_as_float(__builtin_amdgcn_readfirstlane(__float_as_int(gvals[1])));

  // ---- stage x tile: thread owns (xr,xc); 5 chunks of 8 ci, 16-B writes ----
  if (tid < XR * XC) {
    const int xr = tid / XC, xc = tid - (tid / XC) * XC;
    const int gy = ty0 - 2 + xr, gx = tx0 - 2 + xc;
    const bool valid = ((unsigned)gy < (unsigned)HH) && ((unsigned)gx < (unsigned)WW);
    const float* xp = x + xbase + (size_t)(gy * WW + gx);
    char* dstb = xsB + (xr * XC + xc) * 16;
#pragma unroll
    for (int c8 = 0; c8 < 5; c8++) {
      unsigned int pk[4];
#pragma unroll
      for (int q = 0; q < 4; q++) {
        int ci0 = c8 * 8 + q * 2, ci1 = ci0 + 1;
        float v0 = (ci0 < CCH && valid) ? xp[(size_t)ci0 << 16] : 0.f;
        float v1 = (ci1 < CCH && valid) ? xp[(size_t)ci1 << 16] : 0.f;
        pk[q] = (unsigned)f2bf(v0) | ((unsigned)f2bf(v1) << 16);
      }
      *(uint4*)(dstb + c8 * 3840) = make_uint4(pk[0], pk[1], pk[2], pk[3]);
    }
  }

  // ---- conv1 pixel coords: T grid 10x18=180 px, 12 slots; wave w owns w,w+4,w+8 ----
  int vimg[3], pst[3], tsoff[3], pb1[3];
#pragma unroll
  for (int i = 0; i < 3; i++) {
    int p = (w + 4 * i) * 16 + l15;
    int tr = p / TC, tc = p - tr * TC;
    pst[i] = (p < TR * TC) ? 1 : 0;
    int trc = tr < (TR - 1) ? tr : (TR - 1);
    pb1[i] = trc * 320 + tc * 16;
    tsoff[i] = trc * 288 + tc * 16;
    int gy = ty0 - 1 + tr, gx = tx0 - 1 + tc;
    vimg[i] = (pst[i] && (unsigned)gy < (unsigned)HH && (unsigned)gx < (unsigned)WW) ? 1 : 0;
  }
  // precomputed conv1 LDS read bases: b1a[kc][i] = pb1[i] + xkc[kc]
  int b1a[4][3];
#pragma unroll
  for (int kc = 0; kc < 4; kc++) {
    int k0 = kc * 32 + kl * 8;
    int d = (k0 >= 80) ? 2 : (k0 >= 40 ? 1 : 0);
    int xkc = (k0 < 120) ? (((k0 - 40 * d) >> 3) * 3840 + d * 320) : 0;
#pragma unroll
    for (int i = 0; i < 3; i++) b1a[kc][i] = pb1[i] + xkc;
  }
  // GELU store base: addr = tsStore[i] + mt*5760  (co0=mt*16+kl*4)
  int tsStore[3];
#pragma unroll
  for (int i = 0; i < 3; i++) tsStore[i] = tsoff[i] + (kl >> 1) * 2880 + (kl & 1) * 8;

  // conv2: 8 rows; wave w owns rows w, w+4; col = l15. b2[kc][i] precomputed.
  int b2a[7][2];
#pragma unroll
  for (int kc = 0; kc < 7; kc++) {
    int k0 = kc * 32 + kl * 8;
    int d = (k0 >= 144) ? 2 : (k0 >= 72 ? 1 : 0);
    int tkc = (k0 < 216) ? (((k0 - 72 * d) >> 3) * 2880 + d * 288) : 0;
#pragma unroll
    for (int i = 0; i < 2; i++) b2a[kc][i] = (w + 4 * i) * 288 + l15 * 16 + tkc;
  }

  const int lob = lane * 8;   // lane element offset (16 B) for weight fragments

  f32x4 yacc[2][3];
#pragma unroll
  for (int i = 0; i < 2; i++)
#pragma unroll
    for (int mt = 0; mt < 3; mt++) yacc[i][mt] = (f32x4){0.f, 0.f, 0.f, 0.f};

  __syncthreads();

#pragma unroll
  for (int ei = 0; ei < 2; ei++) {
    if (ei >= ne) break;
    const float gv = ei ? g1 : g0;
    const unsigned short* w1p = wt1 + (ei ? e1 : e0) * 30720;   // SGPR base
    const unsigned short* w2p = wt2 + (ei ? e1 : e0) * 32256;   // SGPR base

    // ================= conv1: kc-major, in-place frag rotation =================
    f32x4 acc[3][5];
#pragma unroll
    for (int i = 0; i < 3; i++)
#pragma unroll
      for (int mt = 0; mt < 5; mt++) acc[i][mt] = (f32x4){0.f, 0.f, 0.f, 0.f};

    bf16x8 f1[3][5];   // one kc column: [dx][mt]
#pragma unroll
    for (int dx = 0; dx < 3; dx++)
#pragma unroll
      for (int mt = 0; mt < 5; mt++)
        f1[dx][mt] = *(const bf16x8*)(w1p + (dx * 4) * 5 * 512 + mt * 512 + lob);

#pragma unroll
    for (int kc = 0; kc < 4; kc++) {
#pragma unroll
      for (int dx = 0; dx < 3; dx++) {
        bf16x8 bv[3];
#pragma unroll
        for (int i = 0; i < 3; i++)
          bv[i] = *(const bf16x8*)(xsB + b1a[kc][i] + dx * 16);
        __builtin_amdgcn_s_setprio(1);
#pragma unroll
        for (int mt = 0; mt < 5; mt++) {
#pragma unroll
          for (int i = 0; i < 3; i++)
            acc[i][mt] = __builtin_amdgcn_mfma_f32_16x16x32_bf16(f1[dx][mt], bv[i], acc[i][mt], 0, 0, 0);
        }
        __builtin_amdgcn_s_setprio(0);
        if (kc < 3) {   // reload this dx's frags for kc+1; reused one full kc step later
#pragma unroll
          for (int mt = 0; mt < 5; mt++)
            f1[dx][mt] = *(const bf16x8*)(w1p + ((dx * 4 + kc + 1) * 5 + mt) * 512 + lob);
        }
      }
    }

    // ---- conv2 dx=0 frag batch: issued here, latency hidden under GELU ----
    bf16x8 f2[7][3];
#pragma unroll
    for (int kc = 0; kc < 7; kc++)
#pragma unroll
      for (int mt = 0; mt < 3; mt++)
        f2[kc][mt] = *(const bf16x8*)(w2p + (kc * 3 + mt) * 512 + lob);

    // ---- GELU * gate + store T (8-B packed; co 72..79 land in LDS junk pad) ----
#pragma unroll
    for (int i = 0; i < 3; i++) {
      if (pst[i]) {
#pragma unroll
        for (int mt = 0; mt < 5; mt++) {
          float v0 = vimg[i] ? gv * gelu_fast(acc[i][mt].x) : 0.f;
          float v1 = vimg[i] ? gv * gelu_fast(acc[i][mt].y) : 0.f;
          float v2 = vimg[i] ? gv * gelu_fast(acc[i][mt].z) : 0.f;
          float v3 = vimg[i] ? gv * gelu_fast(acc[i][mt].w) : 0.f;
          unsigned int lo = (unsigned)f2bf(v0) | ((unsigned)f2bf(v1) << 16);
          unsigned int hi = (unsigned)f2bf(v2) | ((unsigned)f2bf(v3) << 16);
          *(uint2*)(tsB + tsStore[i] + mt * 5760) = make_uint2(lo, hi);
        }
      }
    }
    __syncthreads();

    // ================= conv2: dx-major, in-place frag rotation, acc -> yacc =========
#pragma unroll
    for (int dx = 0; dx < 3; dx++) {
#pragma unroll
      for (int kc = 0; kc < 7; kc++) {
        bf16x8 bv0 = *(const bf16x8*)(tsB + b2a[kc][0] + dx * 16);
        bf16x8 bv1 = *(const bf16x8*)(tsB + b2a[kc][1] + dx * 16);
        __builtin_amdgcn_s_setprio(1);
#pragma unroll
        for (int mt = 0; mt < 3; mt++) {
          yacc[0][mt] = __builtin_amdgcn_mfma_f32_16x16x32_bf16(f2[kc][mt], bv0, yacc[0][mt], 0, 0, 0);
          yacc[1][mt] = __builtin_amdgcn_mfma_f32_16x16x32_bf16(f2[kc][mt], bv1, yacc[1][mt], 0, 0, 0);
        }
        __builtin_amdgcn_s_setprio(0);
        if (dx < 2) {   // reload this kc's frags for dx+1; reused one full dx sweep later
#pragma unroll
          for (int mt = 0; mt < 3; mt++)
            f2[kc][mt] = *(const bf16x8*)(w2p + (((dx + 1) * 7 + kc) * 3 + mt) * 512 + lob);
        }
      }
    }
    __syncthreads();   // ts free for next expert
  }

  // ---- store y (f32) ----
#pragma unroll
  for (int i = 0; i < 2; i++) {
    int row = w + 4 * i;
#pragma unroll
    for (int mt = 0; mt < 3; mt++) {
#pragma unroll
      for (int r = 0; r < 4; r++) {
        int co = mt * 16 + kl * 4 + r;
        if (co < CCH) {
          float v = (r == 0) ? yacc[i][mt].x : (r == 1) ? yacc[i][mt].y
                  : (r == 2) ? yacc[i][mt].z : yacc[i][mt].w;
          y[xbase + ((size_t)co << 16) + (size_t)((ty0 + row) * WW + tx0 + l15)] = v;
        }
      }
    }
  }
}

extern "C" void kernel_launch(void* const* d_in, const int* in_sizes, int n_in,
                              void* d_out, int out_size, void* d_ws, size_t ws_size,
                              hipStream_t stream) {
  const float* x      = (const float*)d_in[0];
  const float* time   = (const float*)d_in[1];
  const float* time_w = (const float*)d_in[2];
  const float* time_b = (const float*)d_in[3];
  const float* gw1    = (const float*)d_in[4];
  const float* gb1    = (const float*)d_in[5];
  const float* gw2    = (const float*)d_in[6];
  const float* gb2    = (const float*)d_in[7];
  const float* w1     = (const float*)d_in[8];
  const float* w2     = (const float*)d_in[9];
  float* out = (float*)d_out;
  float* ws  = (float*)d_ws;
  unsigned short* wt1 = (unsigned short*)((char*)d_ws + WT1_OFF);
  unsigned short* wt2 = (unsigned short*)((char*)d_ws + WT2_OFF);

  hipLaunchKernelGGL(poolwx_kernel, dim3(288 + 756), dim3(256), 0, stream,
                     x, w1, w2, ws, wt1, wt2);
  hipLaunchKernelGGL(gate_kernel, dim3(1), dim3(128), 0, stream,
                     time, time_w, time_b, gw1, gb1, gw2, gb2,
                     ws, out + (size_t)(out_size - 1));
  hipLaunchKernelGGL(conv_kernel, dim3(512, BB), dim3(256), 0, stream,
                     x, wt1, wt2, ws + WS_GATES, out);
}

// Round 11
// 271.761 us; speedup vs baseline: 1.1062x; 1.1062x over previous
//
#include <hip/hip_runtime.h>
#include <hip/hip_bf16.h>
#include <math.h>

#define BB 8
#define CCH 36
#define HH 256
#define WW 256
#define EE 6
#define TDIM 32
#define HID 72
// ws layout: floats [0,288) avg; [288,576) max; [576,624) gates.
// bytes: wt1 frags at 4096 (360 x 1024B); wt2 frags at 372736 (378 x 1024B).
#define WS_GATES (BB*CCH*2)
#define WT1_OFF 4096
#define WT2_OFF (4096 + 368640)

// conv geometry: 16w x 16t output tile, 4 waves, 2 blocks/CU
#define TW 16
#define TH 16
#define XR 20
#define XC 20
#define TR 18
#define TC 18
// LDS strides
#define XROW 320          // XC*16
#define XCHUNK 6400       // XR*XC*16
#define TROW 288          // TC*16
#define TCHUNK 5184       // TR*TC*16

typedef __attribute__((ext_vector_type(8))) short bf16x8;
typedef __attribute__((ext_vector_type(4))) float f32x4;

static __device__ __forceinline__ unsigned short f2bf(float f) {
  __hip_bfloat16 h = __float2bfloat16(f);   // RNE; compiler emits HW cvt
  return *(unsigned short*)&h;
}
// sigmoid-form GELU: x * rcp(1 + exp(-2u)), 2u = x*(1.5958 + 0.07135 x^2).
// exp->inf => rcp->0 => 0; exp->0 => x. |err| ~3e-4, under bf16 noise.
static __device__ __forceinline__ float gelu_fast(float x) {
  float n2u = x * (-1.5957691216f - 0.0713548162f * x * x);
  float r = __builtin_amdgcn_rcpf(1.f + __expf(n2u));
  return x * r;
}

// ---------------- Kernel 1: pool (blocks 0..287) + weight transform (288..1043) ----
// wt1 frag f = ((e*3+dx)*4+kc)*5+mt; elem = f*512 + lane*8 + j.
//   co = mt*16 + (lane&15); k = kc*32 + (lane>>4)*8 + j; k = dy*40+ci, K=120 (pads ZERO).
// wt2 frag f = ((e*3+dx)*7+kc)*3+mt; k = dy*72+ci, K=216 (pads ZERO).
__global__ __launch_bounds__(256) void poolwx_kernel(const float* __restrict__ x,
                                                     const float* __restrict__ w1,
                                                     const float* __restrict__ w2,
                                                     float* __restrict__ ws,
                                                     unsigned short* __restrict__ wt1,
                                                     unsigned short* __restrict__ wt2) {
  if (blockIdx.x < 288) {
    const int bc = blockIdx.x;
    const float* p = x + (size_t)bc * (HH * WW);
    float s = 0.f, m = -INFINITY;
    for (int i = threadIdx.x; i < (HH * WW) / 4; i += 256) {
      float4 v = ((const float4*)p)[i];
      s += v.x + v.y + v.z + v.w;
      m = fmaxf(m, fmaxf(fmaxf(v.x, v.y), fmaxf(v.z, v.w)));
    }
    for (int off = 32; off; off >>= 1) {
      s += __shfl_down(s, off);
      m = fmaxf(m, __shfl_down(m, off));
    }
    __shared__ float ss[4], sm[4];
    int wid = threadIdx.x >> 6, lane = threadIdx.x & 63;
    if (lane == 0) { ss[wid] = s; sm[wid] = m; }
    __syncthreads();
    if (threadIdx.x == 0) {
      float S = ss[0] + ss[1] + ss[2] + ss[3];
      float M = fmaxf(fmaxf(sm[0], sm[1]), fmaxf(sm[2], sm[3]));
      ws[bc] = S * (1.f / (HH * WW));
      ws[BB * CCH + bc] = M;
    }
    return;
  }
  int i = (blockIdx.x - 288) * 256 + threadIdx.x;
  const int n1 = 360 * 512;
  if (i < n1) {
    int j = i & 7;
    int lane = (i >> 3) & 63;
    int f = i >> 9;
    int mt = f % 5;  f /= 5;
    int kc = f % 4;  f /= 4;
    int dx = f % 3;  int e = f / 3;
    int co = mt * 16 + (lane & 15);
    int k = kc * 32 + (lane >> 4) * 8 + j;
    int dy = k / 40, ci = k % 40;
    float v = 0.f;
    if (co < HID && k < 120 && ci < CCH)
      v = w1[(((size_t)(e * HID + co) * CCH + ci) * 3 + dy) * 3 + dx];
    wt1[i] = f2bf(v);
  }
  const int n2 = 378 * 512;
  if (i < n2) {
    int j = i & 7;
    int lane = (i >> 3) & 63;
    int f = i >> 9;
    int mt = f % 3;  f /= 3;
    int kc = f % 7;  f /= 7;
    int dx = f % 3;  int e = f / 3;
    int co = mt * 16 + (lane & 15);
    int k = kc * 32 + (lane >> 4) * 8 + j;
    int dy = k / 72, ci = k % 72;
    float v = 0.f;
    if (co < CCH && k < 216)
      v = w2[(((size_t)(e * CCH + co) * HID + ci) * 3 + dy) * 3 + dx];
    wt2[i] = f2bf(v);
  }
}

// ---------------- Kernel 2: gating MLP + top-2 + loss ----------------
__global__ void gate_kernel(const float* __restrict__ time,
                            const float* __restrict__ time_w,
                            const float* __restrict__ time_b,
                            const float* __restrict__ w1, const float* __restrict__ b1,
                            const float* __restrict__ w2, const float* __restrict__ b2,
                            float* __restrict__ ws, float* __restrict__ loss_out) {
  __shared__ float v[BB * HID];
  __shared__ float h[BB * HID];
  __shared__ float logits[BB * EE];
  const int t = threadIdx.x;
  const float* avg = ws;
  const float* mx = ws + BB * CCH;
  for (int i = t; i < BB * HID; i += blockDim.x) {
    int b = i / HID, c = i % HID;
    float base = (c < CCH) ? avg[b * CCH + c] : mx[b * CCH + (c - CCH)];
    float acc = time_b[c];
    for (int k = 0; k < TDIM; k++) acc += time[b * TDIM + k] * time_w[k * HID + c];
    v[i] = base + acc;
  }
  __syncthreads();
  for (int i = t; i < BB * HID; i += blockDim.x) {
    int b = i / HID, c = i % HID;
    float acc = b1[c];
    for (int k = 0; k < HID; k++) acc += v[b * HID + k] * w1[k * HID + c];
    h[i] = acc > 0.f ? acc : 0.01f * acc;
  }
  __syncthreads();
  for (int i = t; i < BB * EE; i += blockDim.x) {
    int b = i / EE, e = i % EE;
    float acc = b2[e];
    for (int k = 0; k < HID; k++) acc += h[b * HID + k] * w2[k * EE + e];
    logits[i] = acc;
  }
  __syncthreads();
  if (t == 0) {
    float imp[EE], ld[EE];
    for (int e = 0; e < EE; e++) { imp[e] = 0.f; ld[e] = 0.f; }
    for (int b = 0; b < BB; b++) {
      int i1 = -1, i2 = -1;
      float v1 = -1e30f, v2 = -1e30f;
      for (int e = 0; e < EE; e++) {
        float lv = logits[b * EE + e];
        if (lv > v1) { v2 = v1; i2 = i1; v1 = lv; i1 = e; }
        else if (lv > v2) { v2 = lv; i2 = e; }
      }
      float e2 = expf(v2 - v1);
      float g1 = 1.f / (1.f + e2), g2 = e2 / (1.f + e2);
      for (int e = 0; e < EE; e++) ws[WS_GATES + b * EE + e] = 0.f;
      ws[WS_GATES + b * EE + i1] = g1;
      ws[WS_GATES + b * EE + i2] = g2;
      imp[i1] += g1; imp[i2] += g2;
      ld[i1] += 1.f; ld[i2] += 1.f;
    }
    float loss = 0.f;
    {
      float m = 0.f; for (int e = 0; e < EE; e++) m += imp[e]; m /= EE;
      float var = 0.f; for (int e = 0; e < EE; e++) { float d = imp[e] - m; var += d * d; }
      var /= (EE - 1);
      loss += var / (m * m + 1e-10f);
      m = 0.f; for (int e = 0; e < EE; e++) m += ld[e]; m /= EE;
      var = 0.f; for (int e = 0; e < EE; e++) { float d = ld[e] - m; var += d * d; }
      var /= (EE - 1);
      loss += var / (m * m + 1e-10f);
    }
    loss_out[0] = 0.01f * loss;
  }
}

// ---------------- Kernel 3: fused MFMA conv1+GELU+conv2, 16x16 tile ----------------
// LDS: xs[c8<5][20][20][16B] = 32000 B; ts[c9<9][18][18][16B] = 46656 B. Total 78656
// -> 2 blocks/CU. Depth-1 register double-buffer for weight A-frags (r9 scheme,
// NO deep rotation: r10 proved it spills). Gate folded into T. conv1: 6 px-slots/wave
// (30 MFMA cover per frag-group); conv2: 4 row-slots/wave (12 MFMA cover).
__global__ __launch_bounds__(256, 2) void conv_kernel(
    const float* __restrict__ x,
    const unsigned short* __restrict__ wt1,
    const unsigned short* __restrict__ wt2,
    const float* __restrict__ wsg,
    float* __restrict__ y) {
  __shared__ __align__(16) char lds[78656];
  char* xsB = lds;             // 32000 B
  char* tsB = lds + 32000;     // 46656 B

  const int tid = threadIdx.x;
  const int w = tid >> 6;
  const int lane = tid & 63;
  const int l15 = lane & 15;
  const int kl = lane >> 4;
  const int b = blockIdx.y;
  // XCD-chunked swizzle: each XCD gets 32 contiguous tiles (2 tile-rows).
  const int tileId = (blockIdx.x & 7) * 32 + (blockIdx.x >> 3);
  const int tx0 = (tileId & 15) * TW;
  const int ty0 = (tileId >> 4) * TH;
  const size_t xbase = (size_t)b * (CCH * HH * WW);

  // active experts -> wave-uniform scalars
  int eids[2] = {0, 0};
  float gvals[2] = {0.f, 0.f};
  int ne = 0;
  for (int e = 0; e < EE; e++) {
    float g = wsg[b * EE + e];
    if (g != 0.f && ne < 2) { eids[ne] = e; gvals[ne] = g; ne++; }
  }
  ne = __builtin_amdgcn_readfirstlane(ne);
  const int e0 = __builtin_amdgcn_readfirstlane(eids[0]);
  const int e1 = __builtin_amdgcn_readfirstlane(eids[1]);
  const float g0 = __int_as_float(__builtin_amdgcn_readfirstlane(__float_as_int(gvals[0])));
  const float g1 = __int_as_float(__builtin_amdgcn_readfirstlane(__float_as_int(gvals[1])));

  // ---- stage x tile: 400 px, thread owns up to 2; 5 chunks of 8 ci, 16-B writes ----
#pragma unroll
  for (int it = 0; it < 2; it++) {
    int pidx = tid + it * 256;
    if (pidx < XR * XC) {
      const int xr = pidx / XC, xc = pidx - (pidx / XC) * XC;
      const int gy = ty0 - 2 + xr, gx = tx0 - 2 + xc;
      const bool valid = ((unsigned)gy < (unsigned)HH) && ((unsigned)gx < (unsigned)WW);
      const float* xp = x + xbase + (size_t)(gy * WW + gx);
      char* dstb = xsB + pidx * 16;
#pragma unroll
      for (int c8 = 0; c8 < 5; c8++) {
        unsigned int pk[4];
#pragma unroll
        for (int q = 0; q < 4; q++) {
          int ci0 = c8 * 8 + q * 2, ci1 = ci0 + 1;
          float v0 = (ci0 < CCH && valid) ? xp[(size_t)ci0 << 16] : 0.f;
          float v1 = (ci1 < CCH && valid) ? xp[(size_t)ci1 << 16] : 0.f;
          pk[q] = (unsigned)f2bf(v0) | ((unsigned)f2bf(v1) << 16);
        }
        *(uint4*)(dstb + c8 * XCHUNK) = make_uint4(pk[0], pk[1], pk[2], pk[3]);
      }
    }
  }

  // ---- conv1 pixel slots: T grid 18x18=324 px, 21 live slots; wave w: w+4i, i<6 ----
  int vimg[6], pst[6], pb1[6], tsoff[6];
#pragma unroll
  for (int i = 0; i < 6; i++) {
    int p = (w + 4 * i) * 16 + l15;
    int tr = p / TC, tc = p - (p / TC) * TC;
    pst[i] = (p < TR * TC) ? 1 : 0;
    int trc = tr < (TR - 1) ? tr : (TR - 1);
    pb1[i] = trc * XROW + tc * 16;
    tsoff[i] = trc * TROW + tc * 16 + (kl >> 1) * TCHUNK + (kl & 1) * 8;
    int gy = ty0 - 1 + tr, gx = tx0 - 1 + tc;
    vimg[i] = (pst[i] && (unsigned)gy < (unsigned)HH && (unsigned)gx < (unsigned)WW) ? 1 : 0;
  }
  // conv1 K-chunk offsets (invalid k -> 0; weight rows there are ZERO)
  int xkc[4];
#pragma unroll
  for (int kc = 0; kc < 4; kc++) {
    int k0 = kc * 32 + kl * 8;
    int d = (k0 >= 80) ? 2 : (k0 >= 40 ? 1 : 0);
    xkc[kc] = (k0 < 120) ? (((k0 - 40 * d) >> 3) * XCHUNK + d * XROW) : 0;
  }

  const int lob = lane * 8;   // lane element offset (16 B) in weight fragments

  f32x4 yacc[4][3];
#pragma unroll
  for (int i = 0; i < 4; i++)
#pragma unroll
    for (int mt = 0; mt < 3; mt++) yacc[i][mt] = (f32x4){0.f, 0.f, 0.f, 0.f};

  __syncthreads();

#pragma unroll
  for (int ei = 0; ei < 2; ei++) {
    if (ei >= ne) break;
    const float gv = ei ? g1 : g0;
    const unsigned short* w1p = wt1 + (ei ? e1 : e0) * 30720;   // SGPR base
    const unsigned short* w2p = wt2 + (ei ? e1 : e0) * 32256;   // SGPR base

    // ================= conv1: 12 steps (dx*4+kc), A depth-1 double-buffer ==========
    f32x4 acc[6][5];
#pragma unroll
    for (int i = 0; i < 6; i++)
#pragma unroll
      for (int mt = 0; mt < 5; mt++) acc[i][mt] = (f32x4){0.f, 0.f, 0.f, 0.f};

    bf16x8 aA[5], aB[5];
#pragma unroll
    for (int mt = 0; mt < 5; mt++) aA[mt] = *(const bf16x8*)(w1p + mt * 512 + lob);

#pragma unroll
    for (int jj = 0; jj < 12; jj++) {
      if (jj < 11) {
#pragma unroll
        for (int mt = 0; mt < 5; mt++)
          ((jj & 1) ? aA : aB)[mt] = *(const bf16x8*)(w1p + ((jj + 1) * 5 + mt) * 512 + lob);
      }
      const int kc = jj & 3;
      const int dxo = (jj >> 2) * 16;
      bf16x8 bv[6];
#pragma unroll
      for (int i = 0; i < 6; i++)
        bv[i] = *(const bf16x8*)(xsB + pb1[i] + xkc[kc] + dxo);
      __builtin_amdgcn_s_setprio(1);
#pragma unroll
      for (int mt = 0; mt < 5; mt++) {
        bf16x8 av = ((jj & 1) ? aB : aA)[mt];
#pragma unroll
        for (int i = 0; i < 6; i++)
          acc[i][mt] = __builtin_amdgcn_mfma_f32_16x16x32_bf16(av, bv[i], acc[i][mt], 0, 0, 0);
      }
      __builtin_amdgcn_s_setprio(0);
    }

    // preload conv2 first frag-group (latency hides under GELU/store)
    bf16x8 cA[3], cB[3];
#pragma unroll
    for (int mt = 0; mt < 3; mt++) cA[mt] = *(const bf16x8*)(w2p + mt * 512 + lob);

    // ---- gate*GELU + store T (8-B packed; co>=72 skipped by lane predicate) ----
#pragma unroll
    for (int i = 0; i < 6; i++) {
      if (pst[i]) {
#pragma unroll
        for (int mt = 0; mt < 5; mt++) {
          if (mt < 4 || kl < 2) {   // co0 = mt*16+kl*4 < 72
            float v0 = vimg[i] ? gv * gelu_fast(acc[i][mt].x) : 0.f;
            float v1 = vimg[i] ? gv * gelu_fast(acc[i][mt].y) : 0.f;
            float v2 = vimg[i] ? gv * gelu_fast(acc[i][mt].z) : 0.f;
            float v3 = vimg[i] ? gv * gelu_fast(acc[i][mt].w) : 0.f;
            unsigned int lo = (unsigned)f2bf(v0) | ((unsigned)f2bf(v1) << 16);
            unsigned int hi = (unsigned)f2bf(v2) | ((unsigned)f2bf(v3) << 16);
            *(uint2*)(tsB + tsoff[i] + mt * (2 * TCHUNK)) = make_uint2(lo, hi);
          }
        }
      }
    }
    __syncthreads();

    // conv2 addressing (computed here so it reuses acc's dead registers)
    int tkc[7];
#pragma unroll
    for (int kc = 0; kc < 7; kc++) {
      int k0 = kc * 32 + kl * 8;
      int d = (k0 >= 144) ? 2 : (k0 >= 72 ? 1 : 0);
      tkc[kc] = (k0 < 216) ? (((k0 - 72 * d) >> 3) * TCHUNK + d * TROW) : 0;
    }
    int pb2[4];
#pragma unroll
    for (int i = 0; i < 4; i++) pb2[i] = (w + 4 * i) * TROW + l15 * 16;

    // ================= conv2: 21 steps (dx*7+kc), accumulate into yacc =============
#pragma unroll
    for (int jj = 0; jj < 21; jj++) {
      if (jj < 20) {
#pragma unroll
        for (int mt = 0; mt < 3; mt++)
          ((jj & 1) ? cA : cB)[mt] = *(const bf16x8*)(w2p + ((jj + 1) * 3 + mt) * 512 + lob);
      }
      const int kc = jj % 7;
      const int dxo = (jj / 7) * 16;
      bf16x8 bv[4];
#pragma unroll
      for (int i = 0; i < 4; i++)
        bv[i] = *(const bf16x8*)(tsB + pb2[i] + tkc[kc] + dxo);
      __builtin_amdgcn_s_setprio(1);
#pragma unroll
      for (int mt = 0; mt < 3; mt++) {
        bf16x8 av = ((jj & 1) ? cB : cA)[mt];
#pragma unroll
        for (int i = 0; i < 4; i++)
          yacc[i][mt] = __builtin_amdgcn_mfma_f32_16x16x32_bf16(av, bv[i], yacc[i][mt], 0, 0, 0);
      }
      __builtin_amdgcn_s_setprio(0);
    }
    __syncthreads();   // ts free for next expert
  }

  // ---- store y (f32): rows w+4i, col l15 ----
#pragma unroll
  for (int i = 0; i < 4; i++) {
    int row = w + 4 * i;
#pragma unroll
    for (int mt = 0; mt < 3; mt++) {
#pragma unroll
      for (int r = 0; r < 4; r++) {
        int co = mt * 16 + kl * 4 + r;
        if (co < CCH) {
          float v = (r == 0) ? yacc[i][mt].x : (r == 1) ? yacc[i][mt].y
                  : (r == 2) ? yacc[i][mt].z : yacc[i][mt].w;
          y[xbase + ((size_t)co << 16) + (size_t)((ty0 + row) * WW + tx0 + l15)] = v;
        }
      }
    }
  }
}

extern "C" void kernel_launch(void* const* d_in, const int* in_sizes, int n_in,
                              void* d_out, int out_size, void* d_ws, size_t ws_size,
                              hipStream_t stream) {
  const float* x      = (const float*)d_in[0];
  const float* time   = (const float*)d_in[1];
  const float* time_w = (const float*)d_in[2];
  const float* time_b = (const float*)d_in[3];
  const float* gw1    = (const float*)d_in[4];
  const float* gb1    = (const float*)d_in[5];
  const float* gw2    = (const float*)d_in[6];
  const float* gb2    = (const float*)d_in[7];
  const float* w1     = (const float*)d_in[8];
  const float* w2     = (const float*)d_in[9];
  float* out = (float*)d_out;
  float* ws  = (float*)d_ws;
  unsigned short* wt1 = (unsigned short*)((char*)d_ws + WT1_OFF);
  unsigned short* wt2 = (unsigned short*)((char*)d_ws + WT2_OFF);

  hipLaunchKernelGGL(poolwx_kernel, dim3(288 + 756), dim3(256), 0, stream,
                     x, w1, w2, ws, wt1, wt2);
  hipLaunchKernelGGL(gate_kernel, dim3(1), dim3(128), 0, stream,
                     time, time_w, time_b, gw1, gb1, gw2, gb2,
                     ws, out + (size_t)(out_size - 1));
  hipLaunchKernelGGL(conv_kernel, dim3(256, BB), dim3(256), 0, stream,
                     x, wt1, wt2, ws + WS_GATES, out);
}

// Round 12
// 236.849 us; speedup vs baseline: 1.2693x; 1.1474x over previous
//
#include <hip/hip_runtime.h>
#include <hip/hip_bf16.h>
#include <math.h>

#define BB 8
#define CCH 36
#define HH 256
#define WW 256
#define EE 6
#define TDIM 32
#define HID 72
// ws layout: floats [0,288) avg; [288,576) max; [576,624) gates.
// bytes: wt1 frags at 4096 (360 x 1024B); wt2 frags at 372736 (378 x 1024B).
#define WS_GATES (BB*CCH*2)
#define WT1_OFF 4096
#define WT2_OFF (4096 + 368640)

// conv geometry: 16w x 8t output tile, 4 waves (r9 geometry — best verified)
#define TW 16
#define TH 8
#define XR 12
#define XC 20
#define TR 10
#define TC 18

typedef __attribute__((ext_vector_type(8))) short bf16x8;
typedef __attribute__((ext_vector_type(4))) float f32x4;

static __device__ __forceinline__ unsigned short f2bf(float f) {
  __hip_bfloat16 h = __float2bfloat16(f);   // RNE; compiler emits HW cvt
  return *(unsigned short*)&h;
}
// sigmoid-form GELU: x * rcp(1 + exp(-2u)), 2u = x*(1.5958 + 0.07135 x^2).
// exp->inf => rcp->0 => 0; exp->0 => x. |err| ~3e-4, under bf16 noise.
static __device__ __forceinline__ float gelu_fast(float x) {
  float n2u = x * (-1.5957691216f - 0.0713548162f * x * x);
  float r = __builtin_amdgcn_rcpf(1.f + __expf(n2u));
  return x * r;
}

// ---------------- Kernel 1: pool (blocks 0..287) + weight transform (288..1043) ----
// wt1 frag f = ((e*3+dx)*4+kc)*5+mt; elem = f*512 + lane*8 + j.
//   co = mt*16 + (lane&15); k = kc*32 + (lane>>4)*8 + j; k = dy*40+ci, K=120 (pads ZERO).
// wt2 frag f = ((e*3+dx)*7+kc)*3+mt; k = dy*72+ci, K=216 (pads ZERO).
__global__ __launch_bounds__(256) void poolwx_kernel(const float* __restrict__ x,
                                                     const float* __restrict__ w1,
                                                     const float* __restrict__ w2,
                                                     float* __restrict__ ws,
                                                     unsigned short* __restrict__ wt1,
                                                     unsigned short* __restrict__ wt2) {
  if (blockIdx.x < 288) {
    const int bc = blockIdx.x;
    const float* p = x + (size_t)bc * (HH * WW);
    float s = 0.f, m = -INFINITY;
    for (int i = threadIdx.x; i < (HH * WW) / 4; i += 256) {
      float4 v = ((const float4*)p)[i];
      s += v.x + v.y + v.z + v.w;
      m = fmaxf(m, fmaxf(fmaxf(v.x, v.y), fmaxf(v.z, v.w)));
    }
    for (int off = 32; off; off >>= 1) {
      s += __shfl_down(s, off);
      m = fmaxf(m, __shfl_down(m, off));
    }
    __shared__ float ss[4], sm[4];
    int wid = threadIdx.x >> 6, lane = threadIdx.x & 63;
    if (lane == 0) { ss[wid] = s; sm[wid] = m; }
    __syncthreads();
    if (threadIdx.x == 0) {
      float S = ss[0] + ss[1] + ss[2] + ss[3];
      float M = fmaxf(fmaxf(sm[0], sm[1]), fmaxf(sm[2], sm[3]));
      ws[bc] = S * (1.f / (HH * WW));
      ws[BB * CCH + bc] = M;
    }
    return;
  }
  int i = (blockIdx.x - 288) * 256 + threadIdx.x;
  const int n1 = 360 * 512;
  if (i < n1) {
    int j = i & 7;
    int lane = (i >> 3) & 63;
    int f = i >> 9;
    int mt = f % 5;  f /= 5;
    int kc = f % 4;  f /= 4;
    int dx = f % 3;  int e = f / 3;
    int co = mt * 16 + (lane & 15);
    int k = kc * 32 + (lane >> 4) * 8 + j;
    int dy = k / 40, ci = k % 40;
    float v = 0.f;
    if (co < HID && k < 120 && ci < CCH)
      v = w1[(((size_t)(e * HID + co) * CCH + ci) * 3 + dy) * 3 + dx];
    wt1[i] = f2bf(v);
  }
  const int n2 = 378 * 512;
  if (i < n2) {
    int j = i & 7;
    int lane = (i >> 3) & 63;
    int f = i >> 9;
    int mt = f % 3;  f /= 3;
    int kc = f % 7;  f /= 7;
    int dx = f % 3;  int e = f / 3;
    int co = mt * 16 + (lane & 15);
    int k = kc * 32 + (lane >> 4) * 8 + j;
    int dy = k / 72, ci = k % 72;
    float v = 0.f;
    if (co < CCH && k < 216)
      v = w2[(((size_t)(e * CCH + co) * HID + ci) * 3 + dy) * 3 + dx];
    wt2[i] = f2bf(v);
  }
}

// ---------------- Kernel 2: gating MLP + top-2 + loss ----------------
__global__ void gate_kernel(const float* __restrict__ time,
                            const float* __restrict__ time_w,
                            const float* __restrict__ time_b,
                            const float* __restrict__ w1, const float* __restrict__ b1,
                            const float* __restrict__ w2, const float* __restrict__ b2,
                            float* __restrict__ ws, float* __restrict__ loss_out) {
  __shared__ float v[BB * HID];
  __shared__ float h[BB * HID];
  __shared__ float logits[BB * EE];
  const int t = threadIdx.x;
  const float* avg = ws;
  const float* mx = ws + BB * CCH;
  for (int i = t; i < BB * HID; i += blockDim.x) {
    int b = i / HID, c = i % HID;
    float base = (c < CCH) ? avg[b * CCH + c] : mx[b * CCH + (c - CCH)];
    float acc = time_b[c];
    for (int k = 0; k < TDIM; k++) acc += time[b * TDIM + k] * time_w[k * HID + c];
    v[i] = base + acc;
  }
  __syncthreads();
  for (int i = t; i < BB * HID; i += blockDim.x) {
    int b = i / HID, c = i % HID;
    float acc = b1[c];
    for (int k = 0; k < HID; k++) acc += v[b * HID + k] * w1[k * HID + c];
    h[i] = acc > 0.f ? acc : 0.01f * acc;
  }
  __syncthreads();
  for (int i = t; i < BB * EE; i += blockDim.x) {
    int b = i / EE, e = i % EE;
    float acc = b2[e];
    for (int k = 0; k < HID; k++) acc += h[b * HID + k] * w2[k * EE + e];
    logits[i] = acc;
  }
  __syncthreads();
  if (t == 0) {
    float imp[EE], ld[EE];
    for (int e = 0; e < EE; e++) { imp[e] = 0.f; ld[e] = 0.f; }
    for (int b = 0; b < BB; b++) {
      int i1 = -1, i2 = -1;
      float v1 = -1e30f, v2 = -1e30f;
      for (int e = 0; e < EE; e++) {
        float lv = logits[b * EE + e];
        if (lv > v1) { v2 = v1; i2 = i1; v1 = lv; i1 = e; }
        else if (lv > v2) { v2 = lv; i2 = e; }
      }
      float e2 = expf(v2 - v1);
      float g1 = 1.f / (1.f + e2), g2 = e2 / (1.f + e2);
      for (int e = 0; e < EE; e++) ws[WS_GATES + b * EE + e] = 0.f;
      ws[WS_GATES + b * EE + i1] = g1;
      ws[WS_GATES + b * EE + i2] = g2;
      imp[i1] += g1; imp[i2] += g2;
      ld[i1] += 1.f; ld[i2] += 1.f;
    }
    float loss = 0.f;
    {
      float m = 0.f; for (int e = 0; e < EE; e++) m += imp[e]; m /= EE;
      float var = 0.f; for (int e = 0; e < EE; e++) { float d = imp[e] - m; var += d * d; }
      var /= (EE - 1);
      loss += var / (m * m + 1e-10f);
      m = 0.f; for (int e = 0; e < EE; e++) m += ld[e]; m /= EE;
      var = 0.f; for (int e = 0; e < EE; e++) { float d = ld[e] - m; var += d * d; }
      var /= (EE - 1);
      loss += var / (m * m + 1e-10f);
    }
    loss_out[0] = 0.01f * loss;
  }
}

// ---------------- Kernel 3: fused MFMA conv1+GELU+conv2 (r9 base) ----------------
// Tile 16x8, 4 waves, 3 blocks/CU. Chunked LDS (16-B lane stride):
//   xs[c8<5][12][20][16B] 19200 B; ts[c9<9][10][18][16B] 25920 B + 2880 B junk pad.
// conv1: depth-1 weight prefetch (15-MFMA cluster = 291 cyc/SIMD >= L2 latency).
// conv2: depth-2 weight prefetch (6-MFMA cluster = 116 cyc < 200 -> need 2 steps).
// Gate folded into T: ts = bf16(g*gelu); conv2 accumulates directly into yacc.
__global__ __launch_bounds__(256, 3) void conv_kernel(
    const float* __restrict__ x,
    const unsigned short* __restrict__ wt1,
    const unsigned short* __restrict__ wt2,
    const float* __restrict__ wsg,
    float* __restrict__ y) {
  __shared__ __align__(16) char lds[48000];   // 19200 xs + 25920 ts + 2880 pad
  char* xsB = lds;
  char* tsB = lds + 19200;

  const int tid = threadIdx.x;
  const int w = tid >> 6;
  const int lane = tid & 63;
  const int l15 = lane & 15;
  const int kl = lane >> 4;
  const int b = blockIdx.y;
  // XCD-chunked swizzle: each XCD gets a contiguous 4-tile-row band.
  const int tileId = (blockIdx.x & 7) * 64 + (blockIdx.x >> 3);
  const int tx0 = (tileId & 15) * TW;
  const int ty0 = (tileId >> 4) * TH;
  const size_t xbase = (size_t)b * (CCH * HH * WW);

  // active experts -> wave-uniform scalars
  int eids[2] = {0, 0};
  float gvals[2] = {0.f, 0.f};
  int ne = 0;
  for (int e = 0; e < EE; e++) {
    float g = wsg[b * EE + e];
    if (g != 0.f && ne < 2) { eids[ne] = e; gvals[ne] = g; ne++; }
  }
  ne = __builtin_amdgcn_readfirstlane(ne);
  const int e0 = __builtin_amdgcn_readfirstlane(eids[0]);
  const int e1 = __builtin_amdgcn_readfirstlane(eids[1]);
  const float g0 = __int_as_float(__builtin_amdgcn_readfirstlane(__float_as_int(gvals[0])));
  const float g1 = __int_as_float(__builtin_amdgcn_readfirstlane(__float_as_int(gvals[1])));

  // ---- stage x tile: thread owns (xr,xc); 5 chunks of 8 ci, 16-B writes ----
  if (tid < XR * XC) {
    const int xr = tid / XC, xc = tid - (tid / XC) * XC;
    const int gy = ty0 - 2 + xr, gx = tx0 - 2 + xc;
    const bool valid = ((unsigned)gy < (unsigned)HH) && ((unsigned)gx < (unsigned)WW);
    const float* xp = x + xbase + (size_t)(gy * WW + gx);
    char* dstb = xsB + (xr * XC + xc) * 16;
#pragma unroll
    for (int c8 = 0; c8 < 5; c8++) {
      unsigned int pk[4];
#pragma unroll
      for (int q = 0; q < 4; q++) {
        int ci0 = c8 * 8 + q * 2, ci1 = ci0 + 1;
        float v0 = (ci0 < CCH && valid) ? xp[(size_t)ci0 << 16] : 0.f;
        float v1 = (ci1 < CCH && valid) ? xp[(size_t)ci1 << 16] : 0.f;
        pk[q] = (unsigned)f2bf(v0) | ((unsigned)f2bf(v1) << 16);
      }
      *(uint4*)(dstb + c8 * 3840) = make_uint4(pk[0], pk[1], pk[2], pk[3]);
    }
  }

  // ---- conv1 pixel coords: T grid 10x18=180 px, 12 slots; wave w owns w,w+4,w+8 ----
  int vimg[3], pst[3], tsoff[3], pb1[3];
#pragma unroll
  for (int i = 0; i < 3; i++) {
    int p = (w + 4 * i) * 16 + l15;
    int tr = p / TC, tc = p - tr * TC;
    pst[i] = (p < TR * TC) ? 1 : 0;
    int trc = tr < (TR - 1) ? tr : (TR - 1);
    pb1[i] = trc * 320 + tc * 16;
    tsoff[i] = trc * 288 + tc * 16;
    int gy = ty0 - 1 + tr, gx = tx0 - 1 + tc;
    vimg[i] = (pst[i] && (unsigned)gy < (unsigned)HH && (unsigned)gx < (unsigned)WW) ? 1 : 0;
  }
  // precomputed conv1 LDS read bases: b1a[kc][i] = pb1[i] + xkc[kc]
  int b1a[4][3];
#pragma unroll
  for (int kc = 0; kc < 4; kc++) {
    int k0 = kc * 32 + kl * 8;
    int d = (k0 >= 80) ? 2 : (k0 >= 40 ? 1 : 0);
    int xkc = (k0 < 120) ? (((k0 - 40 * d) >> 3) * 3840 + d * 320) : 0;
#pragma unroll
    for (int i = 0; i < 3; i++) b1a[kc][i] = pb1[i] + xkc;
  }
  // GELU store base: addr = tsStore[i] + mt*5760  (co0=mt*16+kl*4)
  int tsStore[3];
#pragma unroll
  for (int i = 0; i < 3; i++) tsStore[i] = tsoff[i] + (kl >> 1) * 2880 + (kl & 1) * 8;

  // conv2: 8 rows; wave w owns rows w, w+4; col = l15. b2[kc][i] precomputed.
  int b2a[7][2];
#pragma unroll
  for (int kc = 0; kc < 7; kc++) {
    int k0 = kc * 32 + kl * 8;
    int d = (k0 >= 144) ? 2 : (k0 >= 72 ? 1 : 0);
    int tkc = (k0 < 216) ? (((k0 - 72 * d) >> 3) * 2880 + d * 288) : 0;
#pragma unroll
    for (int i = 0; i < 2; i++) b2a[kc][i] = (w + 4 * i) * 288 + l15 * 16 + tkc;
  }

  const int lob = lane * 8;   // lane element offset (16 B) for weight fragments

  f32x4 yacc[2][3];
#pragma unroll
  for (int i = 0; i < 2; i++)
#pragma unroll
    for (int mt = 0; mt < 3; mt++) yacc[i][mt] = (f32x4){0.f, 0.f, 0.f, 0.f};

  __syncthreads();

#pragma unroll
  for (int ei = 0; ei < 2; ei++) {
    if (ei >= ne) break;
    const float gv = ei ? g1 : g0;
    const unsigned short* w1p = wt1 + (ei ? e1 : e0) * 30720;   // SGPR base
    const unsigned short* w2p = wt2 + (ei ? e1 : e0) * 32256;   // SGPR base

    // ================= conv1: 12 steps (dx*4+kc), A depth-1 double-buffer ==========
    f32x4 acc[3][5];
#pragma unroll
    for (int i = 0; i < 3; i++)
#pragma unroll
      for (int mt = 0; mt < 5; mt++) acc[i][mt] = (f32x4){0.f, 0.f, 0.f, 0.f};

    bf16x8 aA[5], aB[5];
#pragma unroll
    for (int mt = 0; mt < 5; mt++) aA[mt] = *(const bf16x8*)(w1p + mt * 512 + lob);

#pragma unroll
    for (int jj = 0; jj < 12; jj++) {
      if (jj < 11) {
#pragma unroll
        for (int mt = 0; mt < 5; mt++)
          ((jj & 1) ? aA : aB)[mt] = *(const bf16x8*)(w1p + ((jj + 1) * 5 + mt) * 512 + lob);
      }
      const int kc = jj & 3;
      const int dxo = (jj >> 2) * 16;   // ds_read offset immediate
      bf16x8 bv[3];
#pragma unroll
      for (int i = 0; i < 3; i++)
        bv[i] = *(const bf16x8*)(xsB + b1a[kc][i] + dxo);
      __builtin_amdgcn_s_setprio(1);
#pragma unroll
      for (int mt = 0; mt < 5; mt++) {
        bf16x8 av = ((jj & 1) ? aB : aA)[mt];
#pragma unroll
        for (int i = 0; i < 3; i++)
          acc[i][mt] = __builtin_amdgcn_mfma_f32_16x16x32_bf16(av, bv[i], acc[i][mt], 0, 0, 0);
      }
      __builtin_amdgcn_s_setprio(0);
    }

    // preload conv2 steps 0 and 1 (depth-2; latency hides under GELU/store)
    bf16x8 c0[3], c1[3], c2[3];
#pragma unroll
    for (int mt = 0; mt < 3; mt++) {
      c0[mt] = *(const bf16x8*)(w2p + mt * 512 + lob);
      c1[mt] = *(const bf16x8*)(w2p + (3 + mt) * 512 + lob);
    }

    // ---- gate*GELU + store T (8-B packed; co 72..79 land in LDS junk pad) ----
#pragma unroll
    for (int i = 0; i < 3; i++) {
      if (pst[i]) {
#pragma unroll
        for (int mt = 0; mt < 5; mt++) {
          float v0 = vimg[i] ? gv * gelu_fast(acc[i][mt].x) : 0.f;
          float v1 = vimg[i] ? gv * gelu_fast(acc[i][mt].y) : 0.f;
          float v2 = vimg[i] ? gv * gelu_fast(acc[i][mt].z) : 0.f;
          float v3 = vimg[i] ? gv * gelu_fast(acc[i][mt].w) : 0.f;
          unsigned int lo = (unsigned)f2bf(v0) | ((unsigned)f2bf(v1) << 16);
          unsigned int hi = (unsigned)f2bf(v2) | ((unsigned)f2bf(v3) << 16);
          *(uint2*)(tsB + tsStore[i] + mt * 5760) = make_uint2(lo, hi);
        }
      }
    }
    __syncthreads();

    // ======= conv2: 21 steps (dx*7+kc), depth-2 rotation, accumulate into yacc =====
#pragma unroll
    for (int jj = 0; jj < 21; jj++) {
      if (jj < 19) {   // load frags for step jj+2 into buffer (jj+2)%3
#pragma unroll
        for (int mt = 0; mt < 3; mt++) {
          bf16x8 v = *(const bf16x8*)(w2p + ((jj + 2) * 3 + mt) * 512 + lob);
          if ((jj % 3) == 0) c2[mt] = v;
          else if ((jj % 3) == 1) c0[mt] = v;
          else c1[mt] = v;
        }
      }
      const int kc = jj % 7;
      const int dxo = (jj / 7) * 16;   // ds_read offset immediate
      bf16x8 bv[2];
#pragma unroll
      for (int i = 0; i < 2; i++)
        bv[i] = *(const bf16x8*)(tsB + b2a[kc][i] + dxo);
      __builtin_amdgcn_s_setprio(1);
#pragma unroll
      for (int mt = 0; mt < 3; mt++) {
        bf16x8 av = ((jj % 3) == 0) ? c0[mt] : ((jj % 3) == 1) ? c1[mt] : c2[mt];
#pragma unroll
        for (int i = 0; i < 2; i++)
          yacc[i][mt] = __builtin_amdgcn_mfma_f32_16x16x32_bf16(av, bv[i], yacc[i][mt], 0, 0, 0);
      }
      __builtin_amdgcn_s_setprio(0);
    }
    __syncthreads();   // ts free for next expert
  }

  // ---- store y (f32) ----
#pragma unroll
  for (int i = 0; i < 2; i++) {
    int row = w + 4 * i;
#pragma unroll
    for (int mt = 0; mt < 3; mt++) {
#pragma unroll
      for (int r = 0; r < 4; r++) {
        int co = mt * 16 + kl * 4 + r;
        if (co < CCH) {
          float v = (r == 0) ? yacc[i][mt].x : (r == 1) ? yacc[i][mt].y
                  : (r == 2) ? yacc[i][mt].z : yacc[i][mt].w;
          y[xbase + ((size_t)co << 16) + (size_t)((ty0 + row) * WW + tx0 + l15)] = v;
        }
      }
    }
  }
}

extern "C" void kernel_launch(void* const* d_in, const int* in_sizes, int n_in,
                              void* d_out, int out_size, void* d_ws, size_t ws_size,
                              hipStream_t stream) {
  const float* x      = (const float*)d_in[0];
  const float* time   = (const float*)d_in[1];
  const float* time_w = (const float*)d_in[2];
  const float* time_b = (const float*)d_in[3];
  const float* gw1    = (const float*)d_in[4];
  const float* gb1    = (const float*)d_in[5];
  const float* gw2    = (const float*)d_in[6];
  const float* gb2    = (const float*)d_in[7];
  const float* w1     = (const float*)d_in[8];
  const float* w2     = (const float*)d_in[9];
  float* out = (float*)d_out;
  float* ws  = (float*)d_ws;
  unsigned short* wt1 = (unsigned short*)((char*)d_ws + WT1_OFF);
  unsigned short* wt2 = (unsigned short*)((char*)d_ws + WT2_OFF);

  hipLaunchKernelGGL(poolwx_kernel, dim3(288 + 756), dim3(256), 0, stream,
                     x, w1, w2, ws, wt1, wt2);
  hipLaunchKernelGGL(gate_kernel, dim3(1), dim3(128), 0, stream,
                     time, time_w, time_b, gw1, gb1, gw2, gb2,
                     ws, out + (size_t)(out_size - 1));
  hipLaunchKernelGGL(conv_kernel, dim3(512, BB), dim3(256), 0, stream,
                     x, wt1, wt2, ws + WS_GATES, out);
}